// Round 10
// baseline (15545.883 us; speedup 1.0000x reference)
//
#include <hip/hip_runtime.h>
#include <math.h>

// Problem constants (fixed by the harness).
#define BB 4096
#define TT 2048
#define LL 100

constexpr int NB = 8;        // R10: 8 batch items per block -> grid 512 = 2 blocks/CU
constexpr int WG = 448;      // 7 waves; wave 3 also carries layer-2 + x-deposit
constexpr int KT = 7;        // K-tiles of 32 ext-slots (224 = 2*112)

#define L2E 1.44269504088896340736f

// R7 core: interleaved-K fused multiply. A_ext[2i]=bf16hi(h_i), A_ext[2i+1]=
// bf16lo(h_i); B_ext[2i]=bf16hi(w_i), B_ext[2i+1]=bf16mid(w_i). ONE pass of
// K_eff=224 computes (ahi+alo)·(bhi+bmid) = h·w + O(2^-18), 7 MFMA/gate.
// R10: TWO BLOCKS PER CU in anti-phase. R8 (setprio) and R9 (wave-fusion)
// proved phase diversity can't come from one barrier domain or one wave.
// Here: NB=8, grid=512, 7 waves x 128 VGPR x 2 blocks = exactly the
// 512-reg/SIMD budget -> 2 co-resident blocks with INDEPENDENT barriers.
// Block A's MFMA phase overlaps block B's update phase. Offset analysis
// (FIFO pipe sharing): phase offset is neutrally stable -- preserved under
// both contention and anti-phase -- so the initial s_sleep stagger on odd
// blocks persists. Items use M-rows 0..7 only (rows 8..15 stay zero).
// LDS: single plane, granule (16B) = kt*64 + (row ^ (row>>3)); b128 reads
// conflict-free; h write-back: one ds_write_b32 per item (2-way on writes,
// counted by PMC, free per m136 -- do not chase).
// SCHEDULE NOTE (R4 lesson): update phase stays BATCHED after all MFMAs.
#define AG(kt, row) (((kt) * 64 + ((row) ^ ((row) >> 3))) * 4)

typedef short bf16x8 __attribute__((ext_vector_type(8)));
typedef float f32x4 __attribute__((ext_vector_type(4)));

union AF { int4 v; bf16x8 f; unsigned int w[4]; };

__device__ __forceinline__ float frcp(float x) { return __builtin_amdgcn_rcpf(x); }
__device__ __forceinline__ float fexp2(float x) {
#if __has_builtin(__builtin_amdgcn_exp2f)
    return __builtin_amdgcn_exp2f(x);
#else
    return exp2f(x);
#endif
}
// log2e pre-folded into weights/biases (v_exp_f32 IS 2^x).
__device__ __forceinline__ float sig2(float xp) { return frcp(1.0f + fexp2(-xp)); }
__device__ __forceinline__ float th2(float xpp) { return 1.0f - 2.0f * frcp(1.0f + fexp2(xpp)); }
__device__ __forceinline__ float ftanh_n(float x) { return th2(2.0f * L2E * x); }

__device__ __forceinline__ unsigned int cvt_pk_bf16(float lo, float hi) {
    unsigned int d;
    asm("v_cvt_pk_bf16_f32 %0, %1, %2" : "=v"(d) : "v"(lo), "v"(hi));
    return d;
}

// Layer-1: gates padded 100->112 unit-slots; wave w owns all 4 gates of one
// 16-slot group. Slot-group permutation {0,1,2,6,3,4,5} puts the PAD group
// (slots 96..111) on wave 3. Layer-2 rides in the pad: B-column col16==8 of
// wave 3 holds W_ih2[g] (hi/mid split, same interleave). Biases enter as the
// exact-fp32 MFMA C-input (binit); x rides input-slot i=100 (ext 200/201;
// lane uu==100 deposits x_{t+1}; B rows 200/201 = W_ih1 hi/mid).
// Frag layouts (HW-verified): A[m=lane&15][k=32kt+8quad+j];
// B[k][n=lane&15]; D col=lane&15, row=quad*4+reg.
__global__ void __launch_bounds__(WG)
__attribute__((amdgpu_waves_per_eu(4)))
lstm2_kernel(const float* __restrict__ input,   // [B,T]
             const float* __restrict__ W_ih1,   // [400,1]
             const float* __restrict__ W_hh1,   // [400,100]
             const float* __restrict__ b_ih1,   // [400]
             const float* __restrict__ b_hh1,   // [400]
             const float* __restrict__ W_ih2,   // [4,100]
             const float* __restrict__ W_hh2,   // [4,1]
             const float* __restrict__ b_ih2,   // [4]
             const float* __restrict__ b_hh2,   // [4]
             float* __restrict__ out)           // [B,T]
{
    __shared__ __align__(16) unsigned int afrag[2][KT * 256];   // 14 KB interleaved hi/lo

    const int tid = threadIdx.x;
    const int wave = tid >> 6;       // 0..6
    const int lane = tid & 63;
    const int col16 = lane & 15;
    const int quad = lane >> 4;
    const int bg0 = blockIdx.x * NB;
    const bool mvalid = (quad < 2);  // items occupy M-rows 0..7 only

    // ---------------- init ----------------
    for (int i = tid; i < 2 * KT * 256; i += WG) (&afrag[0][0])[i] = 0u;

    // slot-group permutation: wave 3 -> group 6 (slots 96..111)
    const int sb = (wave == 3) ? 6 : ((wave < 3) ? wave : wave - 1);
    const int uu = 16 * sb + col16;          // unit-slot owned by this lane
    const bool uvalid = (uu < LL);           // pad slots produce h=0
    const bool l2lane = (wave == 3) && (col16 == 8);   // layer-2 carrier lanes
    const bool xlane = (wave == 3) && (col16 == 4);    // x-depositor lanes (uu==100)
    const bool wr_en = (uu <= 100) && mvalid;          // pads>100 / rows>=8 never write

    // gate scales folding log2e (i,f,o: sigmoid; g: tanh needs 2x)
    const float gsc[4] = {L2E, L2E, 2.0f * L2E, L2E};

    // Persistent B-fragments, interleaved (hi,mid) along K.
    // Normal lanes: W_hh1 rows (+ W_ih1 at i==100); l2lane: W_ih2 rows.
    bf16x8 bb[4][KT];
#pragma unroll
    for (int g = 0; g < 4; ++g)
#pragma unroll
        for (int kt = 0; kt < KT; ++kt)
#pragma unroll
            for (int j = 0; j < 8; ++j) {
                const int k = 32 * kt + 8 * quad + j;   // ext slot
                const int i = k >> 1;                   // input unit
                float w = 0.0f;
                if (i < LL) {
                    if (l2lane)       w = W_ih2[g * LL + i] * gsc[g];
                    else if (uvalid)  w = W_hh1[(100 * g + uu) * LL + i] * gsc[g];
                } else if (i == 100) {
                    if (!l2lane && uvalid) w = W_ih1[100 * g + uu] * gsc[g];
                }
                const unsigned int hh = cvt_pk_bf16(w, 0.0f) & 0xffffu;
                if (!(k & 1)) {
                    bb[g][kt][j] = (short)hh;
                } else {
                    const float wres = w - __uint_as_float(hh << 16);
                    bb[g][kt][j] = (short)(cvt_pk_bf16(wres, 0.0f) & 0xffffu);
                }
            }

    // Exact fp32 biases as the MFMA C-input.
    f32x4 binit[4];
#pragma unroll
    for (int g = 0; g < 4; ++g) {
        float bv = 0.0f;
        if (l2lane)      bv = (b_ih2[g] + b_hh2[g]) * gsc[g];
        else if (uvalid) bv = (b_ih1[100 * g + uu] + b_hh1[100 * g + uu]) * gsc[g];
        binit[g] = (f32x4){bv, bv, bv, bv};
    }

    float c1[4] = {0.f, 0.f, 0.f, 0.f};

    // write offsets: unit u's (hi,lo) pair = both halfwords of dword (u&3)
    // in granule (sb, m + 16*((col16>>2)&3)); one b32 per item r.
    int wofs[4];
#pragma unroll
    for (int r = 0; r < 4; ++r) {
        const int row = 4 * quad + r + 16 * ((col16 >> 2) & 3);
        wofs[r] = AG(sb, row) + (col16 & 3);
    }

    // Layer-2 recurrent state (l2lane only; items m = 4*quad+r, quad<2)
    float wh2s[4], h2v[4] = {0.f, 0.f, 0.f, 0.f}, c2v[4] = {0.f, 0.f, 0.f, 0.f};
#pragma unroll
    for (int g = 0; g < 4; ++g)
        wh2s[g] = l2lane ? W_hh2[g] * gsc[g] : 0.0f;

    __syncthreads();

    // ---- prologue: deposit x_0 (hi|lo packed dword) into phase 0 ----
    if (xlane && mvalid) {
#pragma unroll
        for (int r = 0; r < 4; ++r) {
            const int m = 4 * quad + r;
            const float x0 = input[(size_t)(bg0 + m) * TT];
            const unsigned int hh = cvt_pk_bf16(x0, x0);
            const float hf = __uint_as_float(hh << 16);
            afrag[0][wofs[r]] = cvt_pk_bf16(x0, x0 - hf);
        }
    }
    __syncthreads();

    // ---- anti-phase stagger: odd blocks start ~1.3k cyc late ----
    if (blockIdx.x & 1) {
        __builtin_amdgcn_s_sleep(15);   // ~960 cyc
        __builtin_amdgcn_s_sleep(5);    // ~320 cyc
    }

    // ---------------- time loop (one barrier per step) ----------------
    for (int t = 0; t <= TT; ++t) {
        const int p = t & 1, pn = p ^ 1;

        // wave 3 also runs at t==TT to produce the final layer-2 output
        if (t < TT || wave == 3) {
            // x_{t+1} prefetch (2 lanes' worth of wave 3; L2-resident lines).
            float xnext[4] = {0.f, 0.f, 0.f, 0.f};
            if (xlane && mvalid && t + 1 < TT) {
#pragma unroll
                for (int r = 0; r < 4; ++r)
                    xnext[r] = input[(size_t)(bg0 + 4 * quad + r) * TT + (t + 1)];
            }

            // ---- A-frags (interleaved hi/lo of h1_{t-1}): b128 -> MFMA ----
            AF a[KT];
#pragma unroll
            for (int kt = 0; kt < KT; ++kt)
                a[kt].v = *(const int4*)&afrag[p][AG(kt, lane)];

            // single fused pass: 7 kt x 4 gates, bias preloaded via C
            f32x4 acc[4];
#pragma unroll
            for (int g = 0; g < 4; ++g)
                acc[g] = __builtin_amdgcn_mfma_f32_16x16x32_bf16(a[0].f, bb[g][0], binit[g], 0, 0, 0);
#pragma unroll
            for (int kt = 1; kt < KT; ++kt)
#pragma unroll
                for (int g = 0; g < 4; ++g)
                    acc[g] = __builtin_amdgcn_mfma_f32_16x16x32_bf16(a[kt].f, bb[g][kt], acc[g], 0, 0, 0);

            // ---- layer 2 (l2lane): acc[g][r] = b2 + dot(W_ih2[g], h1_{t-1}[4q+r]) ----
            if (l2lane && mvalid && t >= 1) {
#pragma unroll
                for (int r = 0; r < 4; ++r) {
                    const float p0 = fmaf(wh2s[0], h2v[r], acc[0][r]);
                    const float p1 = fmaf(wh2s[1], h2v[r], acc[1][r]);
                    const float p2 = fmaf(wh2s[2], h2v[r], acc[2][r]);
                    const float p3 = fmaf(wh2s[3], h2v[r], acc[3][r]);
                    const float i2 = sig2(p0), f2 = sig2(p1), g2 = th2(p2), o2 = sig2(p3);
                    c2v[r] = f2 * c2v[r] + i2 * g2;
                    h2v[r] = o2 * ftanh_n(c2v[r]);
                    out[(size_t)(bg0 + 4 * quad + r) * TT + (t - 1)] = h2v[r];
                }
            }

            // ---- layer-1 cell update + single-dword (hi|lo) write-back ----
            if (t < TT) {
#pragma unroll
                for (int r = 0; r < 4; ++r) {
                    // bias and x already inside acc -> gates are acc directly
                    const float iv = sig2(acc[0][r]);
                    const float fv = sig2(acc[1][r]);
                    const float gv = th2(acc[2][r]);
                    const float ov = sig2(acc[3][r]);
                    const float c = fv * c1[r] + iv * gv;
                    c1[r] = c;
                    // valid units: h; lane uu==100 carries x_{t+1}
                    const float h = uvalid ? (ov * ftanh_n(c)) : xnext[r];
                    if (wr_en) {
                        const unsigned int hh = cvt_pk_bf16(h, h);   // low16 = bf16rn(h)
                        const float hf = __uint_as_float(hh << 16);
                        afrag[pn][wofs[r]] = cvt_pk_bf16(h, h - hf); // hi | lo<<16
                    }
                }
            }
        }

        __syncthreads();   // h1_t (afrag[pn]) visible for step t+1
    }
}

extern "C" void kernel_launch(void* const* d_in, const int* in_sizes, int n_in,
                              void* d_out, int out_size, void* d_ws, size_t ws_size,
                              hipStream_t stream) {
    const float* input = (const float*)d_in[0];
    const float* W_ih1 = (const float*)d_in[1];
    const float* W_hh1 = (const float*)d_in[2];
    const float* b_ih1 = (const float*)d_in[3];
    const float* b_hh1 = (const float*)d_in[4];
    const float* W_ih2 = (const float*)d_in[5];
    const float* W_hh2 = (const float*)d_in[6];
    const float* b_ih2 = (const float*)d_in[7];
    const float* b_hh2 = (const float*)d_in[8];
    float* out = (float*)d_out;

    dim3 grid(BB / NB);   // 512 workgroups -> 2 per CU, independent barriers
    dim3 block(WG);       // 448 threads = 7 waves
    lstm2_kernel<<<grid, block, 0, stream>>>(input, W_ih1, W_hh1, b_ih1, b_hh1,
                                             W_ih2, W_hh2, b_ih2, b_hh2, out);
}

// Round 11
// 2310.773 us; speedup vs baseline: 6.7276x; 6.7276x over previous
//
#include <hip/hip_runtime.h>
#include <math.h>

// Problem constants (fixed by the harness).
#define BB 4096
#define TT 2048
#define LL 100

constexpr int NB = 16;       // batch items per block (= MFMA M)
constexpr int WG = 448;      // 7 waves; wave 3 also carries layer-2 + x-deposit
constexpr int KT = 7;        // K-tiles of 32 ext-slots (224 = 2*112)

#define L2E 1.44269504088896340736f

// R7 core (BEST CONFIG, re-established after R9/R10 regressions):
// interleaved-K fused multiply. A_ext[2i]=bf16hi(h_i), A_ext[2i+1]=
// bf16lo(h_i); B_ext[2i]=bf16hi(w_i), B_ext[2i+1]=bf16mid(w_i). ONE pass of
// K_eff=224 computes (ahi+alo)·(bhi+bmid) = h·w + O(2^-18), 7 MFMA/gate,
// 28 MFMA/wave. Biases ride the exact-fp32 MFMA C-input; x rides ext-slots
// 200/201 (lane uu==100 deposits x_{t+1}).
//
// FAILED-MECHANISM LEDGER (do not re-attempt):
//  R4: hand-interleaving trans with producer MFMAs -> +300us stall.
//  R8: wave-parity setprio anti-phase -> null (arbitration cannot desync
//      identical barrier-locked streams; round-robin actively re-syncs).
//  R9: wave-fusion 1 wave/SIMD 2 tiles -> -23% (all latency exposed;
//      compiler DID overlap update-A under MFMA-B, but 1-wave issue lost).
//  R10: 2 blocks/CU via NB=8 + waves_per_eu(4) -> 5.4x regression: compiler
//      targeted 64 VGPR and spilled bb[] (FETCH 50 GB/dispatch scratch).
//      Even spill-free: MFMA count is NB-independent -> 2x work inflation.
// Structural floor: step = MFMA phase (~770 cyc/SIMD) + trans phase (~1365,
// 10 irreducible trans/cell) + ~500 stall; phases serial per barrier.
//
// LDS: single plane, granule (16B) = kt*64 + (row ^ (row>>3)); b128 reads
// conflict-free; h write-back one ds_write_b32/item (2-way, free per m136).
#define AG(kt, row) (((kt) * 64 + ((row) ^ ((row) >> 3))) * 4)

typedef short bf16x8 __attribute__((ext_vector_type(8)));
typedef float f32x4 __attribute__((ext_vector_type(4)));

union AF { int4 v; bf16x8 f; unsigned int w[4]; };

__device__ __forceinline__ float frcp(float x) { return __builtin_amdgcn_rcpf(x); }
__device__ __forceinline__ float fexp2(float x) {
#if __has_builtin(__builtin_amdgcn_exp2f)
    return __builtin_amdgcn_exp2f(x);
#else
    return exp2f(x);
#endif
}
// log2e pre-folded into weights/biases (v_exp_f32 IS 2^x).
__device__ __forceinline__ float sig2(float xp) { return frcp(1.0f + fexp2(-xp)); }
__device__ __forceinline__ float th2(float xpp) { return 1.0f - 2.0f * frcp(1.0f + fexp2(xpp)); }
__device__ __forceinline__ float ftanh_n(float x) { return th2(2.0f * L2E * x); }

__device__ __forceinline__ unsigned int cvt_pk_bf16(float lo, float hi) {
    unsigned int d;
    asm("v_cvt_pk_bf16_f32 %0, %1, %2" : "=v"(d) : "v"(lo), "v"(hi));
    return d;
}

// Layer-1: gates padded 100->112 unit-slots; wave w owns all 4 gates of one
// 16-slot group. Slot-group permutation {0,1,2,6,3,4,5} puts the PAD group
// (slots 96..111) on wave 3 (solo on SIMD3). Layer-2 rides in the pad:
// B-column col16==8 of wave 3 holds W_ih2[g] (hi/mid split, same interleave).
// Frag layouts (HW-verified): A[m=lane&15][k=32kt+8quad+j];
// B[k][n=lane&15]; D col=lane&15, row=quad*4+reg.
__global__ void __launch_bounds__(WG)
__attribute__((amdgpu_waves_per_eu(2, 2)))
lstm2_kernel(const float* __restrict__ input,   // [B,T]
             const float* __restrict__ W_ih1,   // [400,1]
             const float* __restrict__ W_hh1,   // [400,100]
             const float* __restrict__ b_ih1,   // [400]
             const float* __restrict__ b_hh1,   // [400]
             const float* __restrict__ W_ih2,   // [4,100]
             const float* __restrict__ W_hh2,   // [4,1]
             const float* __restrict__ b_ih2,   // [4]
             const float* __restrict__ b_hh2,   // [4]
             float* __restrict__ out)           // [B,T]
{
    __shared__ __align__(16) unsigned int afrag[2][KT * 256];   // 14 KB interleaved hi/lo

    const int tid = threadIdx.x;
    const int wave = tid >> 6;       // 0..6
    const int lane = tid & 63;
    const int col16 = lane & 15;
    const int quad = lane >> 4;
    const int bg0 = blockIdx.x * NB;
    const bool hiprio = (wave >= 4); // SIMD partner of waves 0..2 (R8; harmless)

    // ---------------- init ----------------
    for (int i = tid; i < 2 * KT * 256; i += WG) (&afrag[0][0])[i] = 0u;

    // slot-group permutation: wave 3 -> group 6 (slots 96..111)
    const int sb = (wave == 3) ? 6 : ((wave < 3) ? wave : wave - 1);
    const int uu = 16 * sb + col16;          // unit-slot owned by this lane
    const bool uvalid = (uu < LL);           // pad slots produce h=0
    const bool l2lane = (wave == 3) && (col16 == 8);   // layer-2 carrier lanes
    const bool xlane = (wave == 3) && (col16 == 4);    // x-depositor lanes (uu==100)
    const bool wr_en = (uu <= 100);          // uu>=101 slots stay 0 forever

    // gate scales folding log2e (i,f,o: sigmoid; g: tanh needs 2x)
    const float gsc[4] = {L2E, L2E, 2.0f * L2E, L2E};

    // Persistent B-fragments, interleaved (hi,mid) along K.
    // Normal lanes: W_hh1 rows (+ W_ih1 at i==100); l2lane: W_ih2 rows.
    bf16x8 bb[4][KT];
#pragma unroll
    for (int g = 0; g < 4; ++g)
#pragma unroll
        for (int kt = 0; kt < KT; ++kt)
#pragma unroll
            for (int j = 0; j < 8; ++j) {
                const int k = 32 * kt + 8 * quad + j;   // ext slot
                const int i = k >> 1;                   // input unit
                float w = 0.0f;
                if (i < LL) {
                    if (l2lane)       w = W_ih2[g * LL + i] * gsc[g];
                    else if (uvalid)  w = W_hh1[(100 * g + uu) * LL + i] * gsc[g];
                } else if (i == 100) {
                    if (!l2lane && uvalid) w = W_ih1[100 * g + uu] * gsc[g];
                }
                const unsigned int hh = cvt_pk_bf16(w, 0.0f) & 0xffffu;
                if (!(k & 1)) {
                    bb[g][kt][j] = (short)hh;
                } else {
                    const float wres = w - __uint_as_float(hh << 16);
                    bb[g][kt][j] = (short)(cvt_pk_bf16(wres, 0.0f) & 0xffffu);
                }
            }

    // Exact fp32 biases as the MFMA C-input.
    f32x4 binit[4];
#pragma unroll
    for (int g = 0; g < 4; ++g) {
        float bv = 0.0f;
        if (l2lane)      bv = (b_ih2[g] + b_hh2[g]) * gsc[g];
        else if (uvalid) bv = (b_ih1[100 * g + uu] + b_hh1[100 * g + uu]) * gsc[g];
        binit[g] = (f32x4){bv, bv, bv, bv};
    }

    float c1[4] = {0.f, 0.f, 0.f, 0.f};

    // write offsets: unit u's (hi,lo) pair = both halfwords of dword (u&3)
    // in granule (sb, m + 16*((col16>>2)&3)); one b32 per item r.
    int wofs[4];
#pragma unroll
    for (int r = 0; r < 4; ++r) {
        const int row = 4 * quad + r + 16 * ((col16 >> 2) & 3);
        wofs[r] = AG(sb, row) + (col16 & 3);
    }

    // Layer-2 recurrent state (l2lane only; 4 items per lane, m = 4*quad+r)
    float wh2s[4], h2v[4] = {0.f, 0.f, 0.f, 0.f}, c2v[4] = {0.f, 0.f, 0.f, 0.f};
#pragma unroll
    for (int g = 0; g < 4; ++g)
        wh2s[g] = l2lane ? W_hh2[g] * gsc[g] : 0.0f;

    __syncthreads();

    // ---- prologue: deposit x_0 (hi|lo packed dword) into phase 0 ----
    if (xlane) {
#pragma unroll
        for (int r = 0; r < 4; ++r) {
            const int m = 4 * quad + r;
            const float x0 = input[(size_t)(bg0 + m) * TT];
            const unsigned int hh = cvt_pk_bf16(x0, x0);
            const float hf = __uint_as_float(hh << 16);
            afrag[0][wofs[r]] = cvt_pk_bf16(x0, x0 - hf);
        }
    }
    __syncthreads();

    // ---------------- time loop (one barrier per step) ----------------
    for (int t = 0; t <= TT; ++t) {
        const int p = t & 1, pn = p ^ 1;

        // wave 3 also runs at t==TT to produce the final layer-2 output
        if (t < TT || wave == 3) {
            if (hiprio) __builtin_amdgcn_s_setprio(1);

            // x_{t+1} prefetch (4 lanes of wave 3; L2-resident lines).
            float xnext[4] = {0.f, 0.f, 0.f, 0.f};
            if (xlane && t + 1 < TT) {
#pragma unroll
                for (int r = 0; r < 4; ++r)
                    xnext[r] = input[(size_t)(bg0 + 4 * quad + r) * TT + (t + 1)];
            }

            // ---- A-frags (interleaved hi/lo of h1_{t-1}): b128 -> MFMA ----
            AF a[KT];
#pragma unroll
            for (int kt = 0; kt < KT; ++kt)
                a[kt].v = *(const int4*)&afrag[p][AG(kt, lane)];

            // single fused pass: 7 kt x 4 gates, bias preloaded via C
            f32x4 acc[4];
#pragma unroll
            for (int g = 0; g < 4; ++g)
                acc[g] = __builtin_amdgcn_mfma_f32_16x16x32_bf16(a[0].f, bb[g][0], binit[g], 0, 0, 0);
#pragma unroll
            for (int kt = 1; kt < KT; ++kt)
#pragma unroll
                for (int g = 0; g < 4; ++g)
                    acc[g] = __builtin_amdgcn_mfma_f32_16x16x32_bf16(a[kt].f, bb[g][kt], acc[g], 0, 0, 0);

            if (hiprio) __builtin_amdgcn_s_setprio(0);

            // ---- layer 2 (l2lane): acc[g][r] = b2 + dot(W_ih2[g], h1_{t-1}[4q+r]) ----
            if (l2lane && t >= 1) {
#pragma unroll
                for (int r = 0; r < 4; ++r) {
                    const float p0 = fmaf(wh2s[0], h2v[r], acc[0][r]);
                    const float p1 = fmaf(wh2s[1], h2v[r], acc[1][r]);
                    const float p2 = fmaf(wh2s[2], h2v[r], acc[2][r]);
                    const float p3 = fmaf(wh2s[3], h2v[r], acc[3][r]);
                    const float i2 = sig2(p0), f2 = sig2(p1), g2 = th2(p2), o2 = sig2(p3);
                    c2v[r] = f2 * c2v[r] + i2 * g2;
                    h2v[r] = o2 * ftanh_n(c2v[r]);
                    out[(size_t)(bg0 + 4 * quad + r) * TT + (t - 1)] = h2v[r];
                }
            }

            // ---- layer-1 cell update + single-dword (hi|lo) write-back ----
            if (t < TT) {
#pragma unroll
                for (int r = 0; r < 4; ++r) {
                    // bias and x already inside acc -> gates are acc directly
                    const float iv = sig2(acc[0][r]);
                    const float fv = sig2(acc[1][r]);
                    const float gv = th2(acc[2][r]);
                    const float ov = sig2(acc[3][r]);
                    const float c = fv * c1[r] + iv * gv;
                    c1[r] = c;
                    // valid units: h; lane uu==100 carries x_{t+1}
                    const float h = uvalid ? (ov * ftanh_n(c)) : xnext[r];
                    if (wr_en) {
                        const unsigned int hh = cvt_pk_bf16(h, h);   // low16 = bf16rn(h)
                        const float hf = __uint_as_float(hh << 16);
                        afrag[pn][wofs[r]] = cvt_pk_bf16(h, h - hf); // hi | lo<<16
                    }
                }
            }
        }

        __syncthreads();   // h1_t (afrag[pn]) visible for step t+1
    }
}

extern "C" void kernel_launch(void* const* d_in, const int* in_sizes, int n_in,
                              void* d_out, int out_size, void* d_ws, size_t ws_size,
                              hipStream_t stream) {
    const float* input = (const float*)d_in[0];
    const float* W_ih1 = (const float*)d_in[1];
    const float* W_hh1 = (const float*)d_in[2];
    const float* b_ih1 = (const float*)d_in[3];
    const float* b_hh1 = (const float*)d_in[4];
    const float* W_ih2 = (const float*)d_in[5];
    const float* W_hh2 = (const float*)d_in[6];
    const float* b_ih2 = (const float*)d_in[7];
    const float* b_hh2 = (const float*)d_in[8];
    float* out = (float*)d_out;

    dim3 grid(BB / NB);   // 256 workgroups -> 1 per CU
    dim3 block(WG);       // 448 threads = 7 waves
    lstm2_kernel<<<grid, block, 0, stream>>>(input, W_ih1, W_hh1, b_ih1, b_hh1,
                                             W_ih2, W_hh2, b_ih2, b_hh2, out);
}